// Round 23
// baseline (475.993 us; speedup 1.0000x reference)
//
#include <hip/hip_runtime.h>

// RWKV-7 Tmix (B=4, T=1024, C=1024, H=16, HS=64, H_KV=4)
// Round 22: wkv7 ds_read pipeline deepened to 2-ahead (named C/N/M register
// sets rotated through the unrolled 8-step group; compile-time indices).
// R21's 1-ahead gave 248->235us with VGPR only 40 — deeper named queue
// targets the remaining ~180cyc/step of exposed lgkm latency.
// Everything else = R21 (474.5us, absmax 0.0898).

#define NROWS 4096      // B*T
#define CCH   1024
#define EPSV  0.00064f

typedef __attribute__((ext_vector_type(4))) float f32x4;
typedef __attribute__((ext_vector_type(8))) short bf16x8;

__device__ __forceinline__ unsigned short f2b(float f) {
    unsigned x = __float_as_uint(f);
    return (unsigned short)((x + 0x7fffu + ((x >> 16) & 1u)) >> 16);
}
__device__ __forceinline__ float b2f(unsigned short u) {
    return __uint_as_float(((unsigned)u) << 16);
}

#define LDSTR 40

// ---------------------------------------------------------------------------
// Split-precision MFMA GEMM: C[M,N] = A[M,K]*B[N,K]^T (f32 in/out).
// ---------------------------------------------------------------------------
template<bool TANH>
__global__ __launch_bounds__(256) void gemm_split(
    const float* __restrict__ A, int lda, const float* __restrict__ B, int ldb,
    float* __restrict__ C, int ldc, int M, int N, int K, int tl, int th)
{
    __shared__ __align__(16) unsigned short Ah[128 * LDSTR];
    __shared__ __align__(16) unsigned short Al[128 * LDSTR];
    __shared__ __align__(16) unsigned short Bh[128 * LDSTR];
    __shared__ __align__(16) unsigned short Bl[128 * LDSTR];
    const int t = threadIdx.x;
    const int wave = t >> 6, lane = t & 63;
    const int m0 = blockIdx.y * 128, n0 = blockIdx.x * 128;
    const int wm = (wave >> 1) * 64, wn = (wave & 1) * 64;
    const int fr = lane & 15, kq = lane >> 4;

    f32x4 acc[4][4];
    #pragma unroll
    for (int i = 0; i < 4; ++i)
        #pragma unroll
        for (int j = 0; j < 4; ++j)
            acc[i][j] = (f32x4){0.f, 0.f, 0.f, 0.f};

    const int srow = t >> 3;         // 0..31
    const int scol = (t & 7) * 4;    // 0,4,..,28

    for (int k0 = 0; k0 < K; k0 += 32) {
        #pragma unroll
        for (int p = 0; p < 4; ++p) {
            const int row = p * 32 + srow;
            {
                const float4 v = *reinterpret_cast<const float4*>(
                    A + (size_t)(m0 + row) * lda + k0 + scol);
                ushort4 h, l;
                h.x = f2b(v.x); l.x = f2b(v.x - b2f(h.x));
                h.y = f2b(v.y); l.y = f2b(v.y - b2f(h.y));
                h.z = f2b(v.z); l.z = f2b(v.z - b2f(h.z));
                h.w = f2b(v.w); l.w = f2b(v.w - b2f(h.w));
                *reinterpret_cast<ushort4*>(&Ah[row * LDSTR + scol]) = h;
                *reinterpret_cast<ushort4*>(&Al[row * LDSTR + scol]) = l;
            }
            {
                float4 v = make_float4(0.f, 0.f, 0.f, 0.f);
                if (n0 + row < N)
                    v = *reinterpret_cast<const float4*>(
                        B + (size_t)(n0 + row) * ldb + k0 + scol);
                ushort4 h, l;
                h.x = f2b(v.x); l.x = f2b(v.x - b2f(h.x));
                h.y = f2b(v.y); l.y = f2b(v.y - b2f(h.y));
                h.z = f2b(v.z); l.z = f2b(v.z - b2f(h.z));
                h.w = f2b(v.w); l.w = f2b(v.w - b2f(h.w));
                *reinterpret_cast<ushort4*>(&Bh[row * LDSTR + scol]) = h;
                *reinterpret_cast<ushort4*>(&Bl[row * LDSTR + scol]) = l;
            }
        }
        __syncthreads();

        bf16x8 ah[4], al[4], bh[4], bl[4];
        #pragma unroll
        for (int mi = 0; mi < 4; ++mi) {
            ah[mi] = *reinterpret_cast<const bf16x8*>(&Ah[(wm + mi * 16 + fr) * LDSTR + kq * 8]);
            al[mi] = *reinterpret_cast<const bf16x8*>(&Al[(wm + mi * 16 + fr) * LDSTR + kq * 8]);
        }
        #pragma unroll
        for (int ni = 0; ni < 4; ++ni) {
            bh[ni] = *reinterpret_cast<const bf16x8*>(&Bh[(wn + ni * 16 + fr) * LDSTR + kq * 8]);
            bl[ni] = *reinterpret_cast<const bf16x8*>(&Bl[(wn + ni * 16 + fr) * LDSTR + kq * 8]);
        }
        #pragma unroll
        for (int mi = 0; mi < 4; ++mi)
            #pragma unroll
            for (int ni = 0; ni < 4; ++ni) {
                acc[mi][ni] = __builtin_amdgcn_mfma_f32_16x16x32_bf16(
                    al[mi], bh[ni], acc[mi][ni], 0, 0, 0);
                acc[mi][ni] = __builtin_amdgcn_mfma_f32_16x16x32_bf16(
                    ah[mi], bl[ni], acc[mi][ni], 0, 0, 0);
                acc[mi][ni] = __builtin_amdgcn_mfma_f32_16x16x32_bf16(
                    ah[mi], bh[ni], acc[mi][ni], 0, 0, 0);
            }
        __syncthreads();
    }

    const int crow0 = m0 + wm + kq * 4;
    const int ccol0 = n0 + wn + fr;
    #pragma unroll
    for (int mi = 0; mi < 4; ++mi)
        #pragma unroll
        for (int ni = 0; ni < 4; ++ni) {
            const int col = ccol0 + ni * 16;
            if (col < N) {
                #pragma unroll
                for (int i = 0; i < 4; ++i) {
                    float v = acc[mi][ni][i];
                    if (TANH && col >= tl && col < th) v = tanhf(v);
                    C[(size_t)(crow0 + mi * 16 + i) * ldc + col] = v;
                }
            }
        }
}

// ---------------------------------------------------------------------------
// Plain bf16 MFMA GEMM, generalized dims (r-GEMM, out-GEMM).
// ---------------------------------------------------------------------------
__global__ __launch_bounds__(256) void gemm_mfma(
    const float* __restrict__ A, int lda, const float* __restrict__ B, int ldb,
    float* __restrict__ C, int ldc, int M, int N, int K)
{
    __shared__ __align__(16) unsigned short Ah[128 * LDSTR];
    __shared__ __align__(16) unsigned short Bh[128 * LDSTR];
    const int t = threadIdx.x;
    const int wave = t >> 6, lane = t & 63;
    const int m0 = blockIdx.y * 128, n0 = blockIdx.x * 128;
    const int wm = (wave >> 1) * 64, wn = (wave & 1) * 64;
    const int fr = lane & 15, kq = lane >> 4;

    f32x4 acc[4][4];
    #pragma unroll
    for (int i = 0; i < 4; ++i)
        #pragma unroll
        for (int j = 0; j < 4; ++j)
            acc[i][j] = (f32x4){0.f, 0.f, 0.f, 0.f};

    const int srow = t >> 3;
    const int scol = (t & 7) * 4;

    for (int k0 = 0; k0 < K; k0 += 32) {
        #pragma unroll
        for (int p = 0; p < 4; ++p) {
            const int row = p * 32 + srow;
            const float4 av = *reinterpret_cast<const float4*>(
                A + (size_t)(m0 + row) * lda + k0 + scol);
            ushort4 a4;
            a4.x = f2b(av.x); a4.y = f2b(av.y); a4.z = f2b(av.z); a4.w = f2b(av.w);
            *reinterpret_cast<ushort4*>(&Ah[row * LDSTR + scol]) = a4;
            const float4 bv = *reinterpret_cast<const float4*>(
                B + (size_t)(n0 + row) * ldb + k0 + scol);
            ushort4 b4;
            b4.x = f2b(bv.x); b4.y = f2b(bv.y); b4.z = f2b(bv.z); b4.w = f2b(bv.w);
            *reinterpret_cast<ushort4*>(&Bh[row * LDSTR + scol]) = b4;
        }
        __syncthreads();

        bf16x8 af[4], bfr[4];
        #pragma unroll
        for (int mi = 0; mi < 4; ++mi)
            af[mi] = *reinterpret_cast<const bf16x8*>(&Ah[(wm + mi * 16 + fr) * LDSTR + kq * 8]);
        #pragma unroll
        for (int ni = 0; ni < 4; ++ni)
            bfr[ni] = *reinterpret_cast<const bf16x8*>(&Bh[(wn + ni * 16 + fr) * LDSTR + kq * 8]);
        #pragma unroll
        for (int mi = 0; mi < 4; ++mi)
            #pragma unroll
            for (int ni = 0; ni < 4; ++ni)
                acc[mi][ni] = __builtin_amdgcn_mfma_f32_16x16x32_bf16(
                    af[mi], bfr[ni], acc[mi][ni], 0, 0, 0);
        __syncthreads();
    }

    const int crow0 = m0 + wm + kq * 4;
    const int ccol0 = n0 + wn + fr;
    #pragma unroll
    for (int mi = 0; mi < 4; ++mi)
        #pragma unroll
        for (int ni = 0; ni < 4; ++ni) {
            const int col = ccol0 + ni * 16;
            #pragma unroll
            for (int i = 0; i < 4; ++i)
                C[(size_t)(crow0 + mi * 16 + i) * ldc + col] = acc[mi][ni][i];
        }
}

// ---------------------------------------------------------------------------
// Batched stage-2 GEMM: z=0: dd ; z=1: aa ; z=2: vv.
// ---------------------------------------------------------------------------
__global__ __launch_bounds__(256) void gemm_stage2(
    const float* __restrict__ kvh,
    const float* __restrict__ w2T, const float* __restrict__ a2T,
    const float* __restrict__ v2T,
    float* __restrict__ wdec, float* __restrict__ kf, float* __restrict__ vf)
{
    const int z = blockIdx.z;
    const float* A = kvh + (z == 0 ? 512 : z == 1 ? 576 : 640);
    const float* B = z == 0 ? w2T : z == 1 ? a2T : v2T;
    float* C       = z == 0 ? wdec : z == 1 ? kf : vf;
    const int K    = z == 2 ? 32 : 64;
    const int ldb  = K;

    __shared__ __align__(16) unsigned short Ah[128 * LDSTR];
    __shared__ __align__(16) unsigned short Bh[128 * LDSTR];
    const int t = threadIdx.x;
    const int wave = t >> 6, lane = t & 63;
    const int m0 = blockIdx.y * 128, n0 = blockIdx.x * 128;
    const int wm = (wave >> 1) * 64, wn = (wave & 1) * 64;
    const int fr = lane & 15, kq = lane >> 4;

    f32x4 acc[4][4];
    #pragma unroll
    for (int i = 0; i < 4; ++i)
        #pragma unroll
        for (int j = 0; j < 4; ++j)
            acc[i][j] = (f32x4){0.f, 0.f, 0.f, 0.f};

    const int srow = t >> 3;
    const int scol = (t & 7) * 4;

    for (int k0 = 0; k0 < K; k0 += 32) {
        #pragma unroll
        for (int p = 0; p < 4; ++p) {
            const int row = p * 32 + srow;
            const float4 av = *reinterpret_cast<const float4*>(
                A + (size_t)(m0 + row) * 672 + k0 + scol);
            ushort4 a4;
            a4.x = f2b(av.x); a4.y = f2b(av.y); a4.z = f2b(av.z); a4.w = f2b(av.w);
            *reinterpret_cast<ushort4*>(&Ah[row * LDSTR + scol]) = a4;
            const float4 bv = *reinterpret_cast<const float4*>(
                B + (size_t)(n0 + row) * ldb + k0 + scol);
            ushort4 b4;
            b4.x = f2b(bv.x); b4.y = f2b(bv.y); b4.z = f2b(bv.z); b4.w = f2b(bv.w);
            *reinterpret_cast<ushort4*>(&Bh[row * LDSTR + scol]) = b4;
        }
        __syncthreads();

        bf16x8 af[4], bfr[4];
        #pragma unroll
        for (int mi = 0; mi < 4; ++mi)
            af[mi] = *reinterpret_cast<const bf16x8*>(&Ah[(wm + mi * 16 + fr) * LDSTR + kq * 8]);
        #pragma unroll
        for (int ni = 0; ni < 4; ++ni)
            bfr[ni] = *reinterpret_cast<const bf16x8*>(&Bh[(wn + ni * 16 + fr) * LDSTR + kq * 8]);
        #pragma unroll
        for (int mi = 0; mi < 4; ++mi)
            #pragma unroll
            for (int ni = 0; ni < 4; ++ni)
                acc[mi][ni] = __builtin_amdgcn_mfma_f32_16x16x32_bf16(
                    af[mi], bfr[ni], acc[mi][ni], 0, 0, 0);
        __syncthreads();
    }

    const int crow0 = m0 + wm + kq * 4;
    const int ccol0 = n0 + wn + fr;
    #pragma unroll
    for (int mi = 0; mi < 4; ++mi)
        #pragma unroll
        for (int ni = 0; ni < 4; ++ni) {
            const int col = ccol0 + ni * 16;
            #pragma unroll
            for (int i = 0; i < 4; ++i)
                C[(size_t)(crow0 + mi * 16 + i) * 1024 + col] = acc[mi][ni][i];
        }
}

// ---------------------------------------------------------------------------
// Weight packing.
// ---------------------------------------------------------------------------
__global__ __launch_bounds__(256) void pack_all(
    const float* __restrict__ Wk, const float* __restrict__ Wv,
    const float* __restrict__ w1, const float* __restrict__ a1,
    const float* __restrict__ v1, const float* __restrict__ w2,
    const float* __restrict__ a2, const float* __restrict__ v2,
    float* __restrict__ Wkvh,
    float* __restrict__ w2T, float* __restrict__ a2T, float* __restrict__ v2T)
{
    const int blk = blockIdx.x, t = threadIdx.x;
    if (blk < 512) {
        const float* s = blk < 256 ? Wk + (size_t)blk * 1024
                                   : Wv + (size_t)(blk - 256) * 1024;
        const float4 v = *reinterpret_cast<const float4*>(s + t * 4);
        *reinterpret_cast<float4*>(Wkvh + (size_t)blk * 1024 + t * 4) = v;
    } else if (blk < 672) {
        const int f = blk - 512;     // 0..159
        for (int c = t; c < 1024; c += 256) {
            float val;
            if (f < 64)       val = w1[c * 64 + f];
            else if (f < 128) val = a1[c * 64 + (f - 64)];
            else              val = v1[c * 32 + (f - 128)];
            Wkvh[(size_t)(512 + f) * 1024 + c] = val;
        }
    } else {
        const int c = blk - 672;     // 0..1023
        if (t < 64)       w2T[c * 64 + t]         = w2[t * 1024 + c];
        else if (t < 128) a2T[c * 64 + (t - 64)]  = a2[(t - 64) * 1024 + c];
        else if (t < 160) v2T[c * 32 + (t - 128)] = v2[(t - 128) * 1024 + c];
    }
}

// ---------------------------------------------------------------------------
// Slim fuse_pre (aliased in-place dd/aa/vv — read idx then write idx).
// Also writes the v_first passthrough to out2.
// ---------------------------------------------------------------------------
__global__ __launch_bounds__(256) void fuse_pre(
    const float* __restrict__ kvh,
    const float* __restrict__ v_first, const float* __restrict__ mask,
    const float* __restrict__ w0, const float* __restrict__ a0,
    const float* __restrict__ v0,
    const float* __restrict__ k_k, const float* __restrict__ k_a,
    float* __restrict__ wdec, float* __restrict__ kf, float* __restrict__ vf,
    float* __restrict__ aab, float* __restrict__ bbb,
    float* __restrict__ out2)
{
    const int n = blockIdx.x, t = threadIdx.x;
    const float m = mask[n];
    const bool live = m > 0.f;

    #pragma unroll
    for (int q = 0; q < 4; ++q) {
        const int c = q * 256 + t;
        const size_t idx = (size_t)n * 1024 + c;
        const float dd   = w0[c] + wdec[idx];   // ddl
        const float aacc = a0[c] + kf[idx];     // aal
        const float vacc = v0[c] + vf[idx];     // vvl

        const float u  = -dd;
        const float sp = fmaxf(u, 0.f) + log1pf(expf(-fabsf(u)));
        const float dec = expf(-expf(-sp - 0.6f));
        const float av = 1.f / (1.f + expf(-aacc));
        const float sv = 1.f / (1.f + expf(-vacc));

        const int  ck  = q * 64 + (c & 63);
        const float kr = kvh[(size_t)n * 672 + ck];
        const float vr = kvh[(size_t)n * 672 + 256 + ck];
        const float vfi = v_first[idx];
        const float vv  = vr + (vfi - vr) * sv;

        const float tkk = kr * k_k[c];
        float ss = tkk * tkk;
        #pragma unroll
        for (int off = 32; off > 0; off >>= 1) ss += __shfl_xor(ss, off, 64);
        const float kkv = tkk / fmaxf(sqrtf(ss), 1e-12f);

        wdec[idx] = live ? dec : 1.f;
        kf[idx]   = kr * (1.f + (av - 1.f) * k_a[c]) * m;
        vf[idx]   = vv * m;
        aab[idx]  = -kkv * m;
        bbb[idx]  = kkv * av * m;
        out2[idx] = vfi;                       // v_first passthrough
    }
}

// ---------------------------------------------------------------------------
// WKV7: 256 blocks x 4 waves; wave = (bh, j-quarter, 4 rows). LDS 8-step
// double-buffered groups (layout as R17) + 2-ahead ds_read pipeline
// (named C/N/M regs, compile-time indices). Per group ONE vmcnt(8) + ONE
// raw s_barrier. XCD swizzle: 4 blocks of a bh share blk%8.
// ---------------------------------------------------------------------------
__device__ __forceinline__ float qred16(float x) {
    x += __int_as_float(__builtin_amdgcn_update_dpp(
        0, __float_as_int(x), 0xB1, 0xF, 0xF, true));   // quad_perm xor1
    x += __int_as_float(__builtin_amdgcn_update_dpp(
        0, __float_as_int(x), 0x4E, 0xF, 0xF, true));   // quad_perm xor2
    x += __int_as_float(__builtin_amdgcn_update_dpp(
        0, __float_as_int(x), 0x141, 0xF, 0xF, true));  // row_half_mirror
    x += __int_as_float(__builtin_amdgcn_update_dpp(
        0, __float_as_int(x), 0x140, 0xF, 0xF, true));  // row_mirror
    return x;
}

__global__ __launch_bounds__(256, 1) void wkv7(
    const float* __restrict__ r, const float* __restrict__ wdec,
    const float* __restrict__ kf, const float* __restrict__ vf,
    const float* __restrict__ aab, const float* __restrict__ bbb,
    float* __restrict__ y)
{
    __shared__ __align__(16) float4 sl[2][672];
    const int blk = blockIdx.x;               // 0..255
    const int m  = blk & 7;
    const int s_ = blk >> 3;                  // 0..31
    const int bh = (s_ >> 2) * 8 + m;         // 4 blocks of bh share m -> same XCD
    const int j  = s_ & 3;
    const int b = bh >> 4, h = bh & 15;
    const int tid  = threadIdx.x;
    const int wave = tid >> 6;
    const int lane = tid & 63;
    const int li   = lane & 15;
    const int il   = wave * 4 + (lane >> 4);  // local row 0..15
    const int i    = j * 16 + il;             // value row 0..63
    const size_t cb = (size_t)b * (1024 * 1024) + (size_t)h * 64;

#define GLL16(g, l) __builtin_amdgcn_global_load_lds( \
        (const __attribute__((address_space(1))) unsigned int*)(g), \
        (__attribute__((address_space(3))) unsigned int*)(l), 16, 0, 0)

    // cooperative stage of steps [t0, t0+8) into buffer bf
    auto stage = [&](int t0, int bf) {
        #pragma unroll
        for (int k = 0; k < 3; ++k) {
            const int q = tid + k * 256;
            if (q < 672) {
                const float* gp;
                if (q < 640) {
                    const int s  = q / 80;
                    const int rm = q - s * 80;
                    const int arr = rm >> 4, c16 = rm & 15;
                    const float* base = arr == 0 ? wdec : arr == 1 ? kf
                                      : arr == 2 ? aab : arr == 3 ? bbb : r;
                    gp = base + cb + (size_t)(t0 + s) * 1024 + c16 * 4;
                } else {
                    const int qq = q - 640;
                    const int s = qq >> 2, c4 = qq & 3;
                    gp = vf + cb + (size_t)(t0 + s) * 1024 + j * 16 + c4 * 4;
                }
                // wave-uniform LDS base: slot (wave*64 + k*256); HW adds lane*16
                GLL16(gp, &sl[bf][wave * 64 + k * 256]);
            }
        }
    };

#define RD(S, dX, kX, aX, bX, rX, vX) { \
        dX = sl[bf][(S) * 80 + 0  + li]; \
        kX = sl[bf][(S) * 80 + 16 + li]; \
        aX = sl[bf][(S) * 80 + 32 + li]; \
        bX = sl[bf][(S) * 80 + 48 + li]; \
        rX = sl[bf][(S) * 80 + 64 + li]; \
        vX = reinterpret_cast<const float*>(&sl[bf][640 + (S) * 4])[il]; }

    float4 S = (float4){0.f, 0.f, 0.f, 0.f};

    stage(0, 0);
    asm volatile("s_waitcnt vmcnt(0)" ::: "memory");
    __builtin_amdgcn_sched_barrier(0);
    __builtin_amdgcn_s_barrier();

    for (int g = 0; g < 128; ++g) {
        const int bf = g & 1;
        const int t0 = g * 8;
        if (g + 1 < 128) stage(t0 + 8, bf ^ 1);
        __builtin_amdgcn_sched_barrier(0);   // pin GLLs before compute

        // preload steps 0 and 1 of the group (2-ahead pipeline)
        float4 dC, kC, aC, bC, rC; float vC;
        float4 dN, kN, aN, bN, rN; float vN;
        RD(0, dC, kC, aC, bC, rC, vC);
        RD(1, dN, kN, aN, bN, rN, vN);

        #pragma unroll
        for (int s = 0; s < 8; ++s) {
            // issue step s+2's reads before computing step s
            float4 dM, kM, aM, bM, rM; float vM;
            if (s < 6) { RD(s + 2, dM, kM, aM, bM, rM, vM); }

            float sa = S.x * aC.x + S.y * aC.y + S.z * aC.z + S.w * aC.w;
            sa = qred16(sa);
            S.x = S.x * dC.x + sa * bC.x + vC * kC.x;
            S.y = S.y * dC.y + sa * bC.y + vC * kC.y;
            S.z = S.z * dC.z + sa * bC.z + vC * kC.z;
            S.w = S.w * dC.w + sa * bC.w + vC * kC.w;
            float yv = S.x * rC.x + S.y * rC.y + S.z * rC.z + S.w * rC.w;
            yv = qred16(yv);
            if (li == 0) y[cb + (size_t)(t0 + s) * 1024 + i] = yv;

            if (s < 7) {
                dC = dN; kC = kN; aC = aN; bC = bN; rC = rN; vC = vN;
            }
            if (s < 6) {
                dN = dM; kN = kM; aN = aM; bN = bM; rN = rM; vN = vM;
            }
        }

        // retire this group's 3 staged GLLs; the <=8 newest (y-stores) may remain
        asm volatile("s_waitcnt vmcnt(8)" ::: "memory");
        __builtin_amdgcn_sched_barrier(0);
        __builtin_amdgcn_s_barrier();
    }
#undef RD
#undef GLL16
}

// ---------------------------------------------------------------------------
// Post: groupnorm per (row, head) + rk*v residual
// ---------------------------------------------------------------------------
__global__ __launch_bounds__(256) void fuse_post(
    const float* __restrict__ y, const float* __restrict__ r,
    const float* __restrict__ kf, const float* __restrict__ vf,
    const float* __restrict__ r_k, const float* __restrict__ ln_g, const float* __restrict__ ln_b,
    float* __restrict__ yn)
{
    const int n = blockIdx.x, t = threadIdx.x;
    #pragma unroll
    for (int q = 0; q < 4; ++q) {
        const int c = q * 256 + t;
        const size_t idx = (size_t)n * 1024 + c;
        const float yv = y[idx];
        float s1 = yv, s2 = yv * yv;
        float rk = r[idx] * kf[idx] * r_k[c];
        #pragma unroll
        for (int off = 32; off > 0; off >>= 1) {
            s1 += __shfl_xor(s1, off, 64);
            s2 += __shfl_xor(s2, off, 64);
            rk += __shfl_xor(rk, off, 64);
        }
        const float mu  = s1 * (1.f / 64.f);
        const float var = s2 * (1.f / 64.f) - mu * mu;
        yn[idx] = (yv - mu) * rsqrtf(var + EPSV) * ln_g[c] + ln_b[c]
                  + rk * vf[idx];
    }
}

// ---------------------------------------------------------------------------
extern "C" void kernel_launch(void* const* d_in, const int* in_sizes, int n_in,
                              void* d_out, int out_size, void* d_ws, size_t ws_size,
                              hipStream_t stream)
{
    const float* x       = (const float*)d_in[0];
    const float* v_first = (const float*)d_in[1];
    const float* mask    = (const float*)d_in[2];
    const float* Wr      = (const float*)d_in[3];
    const float* Wk      = (const float*)d_in[4];
    const float* Wv      = (const float*)d_in[5];
    const float* Wo      = (const float*)d_in[6];
    const float* w0      = (const float*)d_in[7];
    const float* w1      = (const float*)d_in[8];
    const float* w2      = (const float*)d_in[9];
    const float* a0      = (const float*)d_in[10];
    const float* a1      = (const float*)d_in[11];
    const float* a2      = (const float*)d_in[12];
    const float* v0      = (const float*)d_in[13];
    const float* v1      = (const float*)d_in[14];
    const float* v2      = (const float*)d_in[15];
    const float* k_k     = (const float*)d_in[16];
    const float* k_a     = (const float*)d_in[17];
    const float* r_k     = (const float*)d_in[18];
    const float* ln_g    = (const float*)d_in[19];
    const float* ln_b    = (const float*)d_in[20];
    float* out = (float*)d_out;

    float* ws = (float*)d_ws;
    const size_t M4 = (size_t)NROWS * CCH;   // 4M elements
    float* rbuf = ws;
    float* wdec = ws + 1 * M4;   // pre-fuse_pre: ddl
    float* kf   = ws + 2 * M4;   // pre-fuse_pre: aal
    float* vf   = ws + 3 * M4;   // pre-fuse_pre: vvl
    float* aab  = ws + 4 * M4;   // post-wkv7: yn
    float* bbb  = ws + 5 * M4;
    float* ybuf = ws + 6 * M4;
    // region-6 temps (dead before wkv7 writes ybuf):
    float* kvh  = ybuf;                          // [4096][672]
    float* w2T  = kvh  + (size_t)NROWS * 672;    // [1024][64]
    float* a2T  = w2T  + (size_t)1024 * 64;      // [1024][64]
    float* v2T  = a2T  + (size_t)1024 * 64;      // [1024][32]
    float* Wkvh = v2T  + (size_t)1024 * 32;      // [672][1024]
    float* yn = aab;

    dim3 blk(256);
    pack_all<<<1696, blk, 0, stream>>>(Wk, Wv, w1, a1, v1, w2, a2, v2,
                                       Wkvh, w2T, a2T, v2T);
    gemm_mfma<<<dim3(8, 32), blk, 0, stream>>>(
        x, 1024, Wr, 1024, rbuf, 1024, NROWS, 1024, 1024);
    gemm_split<true><<<dim3(6, 32), blk, 0, stream>>>(
        x, 1024, Wkvh, 1024, kvh, 672, NROWS, 672, 1024, 512, 576);
    gemm_stage2<<<dim3(8, 32, 3), blk, 0, stream>>>(
        kvh, w2T, a2T, v2T, wdec, kf, vf);
    fuse_pre<<<NROWS, blk, 0, stream>>>(kvh, v_first, mask, w0, a0, v0,
                                        k_k, k_a, wdec, kf, vf, aab, bbb,
                                        out + M4);
    wkv7<<<256, blk, 0, stream>>>(rbuf, wdec, kf, vf, aab, bbb, ybuf);
    fuse_post<<<NROWS, blk, 0, stream>>>(ybuf, rbuf, kf, vf, r_k, ln_g, ln_b, yn);
    gemm_mfma<<<dim3(8, 32), blk, 0, stream>>>(
        yn, 1024, Wo, 1024, out, 1024, NROWS, 1024, 1024);
}

// Round 24
// 473.630 us; speedup vs baseline: 1.0050x; 1.0050x over previous
//
#include <hip/hip_runtime.h>

// RWKV-7 Tmix (B=4, T=1024, C=1024, H=16, HS=64, H_KV=4)
// Round 23 (FINAL): consolidation to the session-best configuration =
// R21 exactly: wkv7 LDS-group kernel with 1-ahead ds_read pipeline (235us;
// 2-ahead in R22 was flat), split-precision kvh GEMM, plain-bf16 r/out/
// stage-2 GEMMs, fused v_first passthrough. 474.5us, absmax 0.0898.
// Session trajectory: 2715 -> 474.5us (5.7x).

#define NROWS 4096      // B*T
#define CCH   1024
#define EPSV  0.00064f

typedef __attribute__((ext_vector_type(4))) float f32x4;
typedef __attribute__((ext_vector_type(8))) short bf16x8;

__device__ __forceinline__ unsigned short f2b(float f) {
    unsigned x = __float_as_uint(f);
    return (unsigned short)((x + 0x7fffu + ((x >> 16) & 1u)) >> 16);
}
__device__ __forceinline__ float b2f(unsigned short u) {
    return __uint_as_float(((unsigned)u) << 16);
}

#define LDSTR 40

// ---------------------------------------------------------------------------
// Split-precision MFMA GEMM: C[M,N] = A[M,K]*B[N,K]^T (f32 in/out).
// ---------------------------------------------------------------------------
template<bool TANH>
__global__ __launch_bounds__(256) void gemm_split(
    const float* __restrict__ A, int lda, const float* __restrict__ B, int ldb,
    float* __restrict__ C, int ldc, int M, int N, int K, int tl, int th)
{
    __shared__ __align__(16) unsigned short Ah[128 * LDSTR];
    __shared__ __align__(16) unsigned short Al[128 * LDSTR];
    __shared__ __align__(16) unsigned short Bh[128 * LDSTR];
    __shared__ __align__(16) unsigned short Bl[128 * LDSTR];
    const int t = threadIdx.x;
    const int wave = t >> 6, lane = t & 63;
    const int m0 = blockIdx.y * 128, n0 = blockIdx.x * 128;
    const int wm = (wave >> 1) * 64, wn = (wave & 1) * 64;
    const int fr = lane & 15, kq = lane >> 4;

    f32x4 acc[4][4];
    #pragma unroll
    for (int i = 0; i < 4; ++i)
        #pragma unroll
        for (int j = 0; j < 4; ++j)
            acc[i][j] = (f32x4){0.f, 0.f, 0.f, 0.f};

    const int srow = t >> 3;         // 0..31
    const int scol = (t & 7) * 4;    // 0,4,..,28

    for (int k0 = 0; k0 < K; k0 += 32) {
        #pragma unroll
        for (int p = 0; p < 4; ++p) {
            const int row = p * 32 + srow;
            {
                const float4 v = *reinterpret_cast<const float4*>(
                    A + (size_t)(m0 + row) * lda + k0 + scol);
                ushort4 h, l;
                h.x = f2b(v.x); l.x = f2b(v.x - b2f(h.x));
                h.y = f2b(v.y); l.y = f2b(v.y - b2f(h.y));
                h.z = f2b(v.z); l.z = f2b(v.z - b2f(h.z));
                h.w = f2b(v.w); l.w = f2b(v.w - b2f(h.w));
                *reinterpret_cast<ushort4*>(&Ah[row * LDSTR + scol]) = h;
                *reinterpret_cast<ushort4*>(&Al[row * LDSTR + scol]) = l;
            }
            {
                float4 v = make_float4(0.f, 0.f, 0.f, 0.f);
                if (n0 + row < N)
                    v = *reinterpret_cast<const float4*>(
                        B + (size_t)(n0 + row) * ldb + k0 + scol);
                ushort4 h, l;
                h.x = f2b(v.x); l.x = f2b(v.x - b2f(h.x));
                h.y = f2b(v.y); l.y = f2b(v.y - b2f(h.y));
                h.z = f2b(v.z); l.z = f2b(v.z - b2f(h.z));
                h.w = f2b(v.w); l.w = f2b(v.w - b2f(h.w));
                *reinterpret_cast<ushort4*>(&Bh[row * LDSTR + scol]) = h;
                *reinterpret_cast<ushort4*>(&Bl[row * LDSTR + scol]) = l;
            }
        }
        __syncthreads();

        bf16x8 ah[4], al[4], bh[4], bl[4];
        #pragma unroll
        for (int mi = 0; mi < 4; ++mi) {
            ah[mi] = *reinterpret_cast<const bf16x8*>(&Ah[(wm + mi * 16 + fr) * LDSTR + kq * 8]);
            al[mi] = *reinterpret_cast<const bf16x8*>(&Al[(wm + mi * 16 + fr) * LDSTR + kq * 8]);
        }
        #pragma unroll
        for (int ni = 0; ni < 4; ++ni) {
            bh[ni] = *reinterpret_cast<const bf16x8*>(&Bh[(wn + ni * 16 + fr) * LDSTR + kq * 8]);
            bl[ni] = *reinterpret_cast<const bf16x8*>(&Bl[(wn + ni * 16 + fr) * LDSTR + kq * 8]);
        }
        #pragma unroll
        for (int mi = 0; mi < 4; ++mi)
            #pragma unroll
            for (int ni = 0; ni < 4; ++ni) {
                acc[mi][ni] = __builtin_amdgcn_mfma_f32_16x16x32_bf16(
                    al[mi], bh[ni], acc[mi][ni], 0, 0, 0);
                acc[mi][ni] = __builtin_amdgcn_mfma_f32_16x16x32_bf16(
                    ah[mi], bl[ni], acc[mi][ni], 0, 0, 0);
                acc[mi][ni] = __builtin_amdgcn_mfma_f32_16x16x32_bf16(
                    ah[mi], bh[ni], acc[mi][ni], 0, 0, 0);
            }
        __syncthreads();
    }

    const int crow0 = m0 + wm + kq * 4;
    const int ccol0 = n0 + wn + fr;
    #pragma unroll
    for (int mi = 0; mi < 4; ++mi)
        #pragma unroll
        for (int ni = 0; ni < 4; ++ni) {
            const int col = ccol0 + ni * 16;
            if (col < N) {
                #pragma unroll
                for (int i = 0; i < 4; ++i) {
                    float v = acc[mi][ni][i];
                    if (TANH && col >= tl && col < th) v = tanhf(v);
                    C[(size_t)(crow0 + mi * 16 + i) * ldc + col] = v;
                }
            }
        }
}

// ---------------------------------------------------------------------------
// Plain bf16 MFMA GEMM, generalized dims (r-GEMM, out-GEMM).
// ---------------------------------------------------------------------------
__global__ __launch_bounds__(256) void gemm_mfma(
    const float* __restrict__ A, int lda, const float* __restrict__ B, int ldb,
    float* __restrict__ C, int ldc, int M, int N, int K)
{
    __shared__ __align__(16) unsigned short Ah[128 * LDSTR];
    __shared__ __align__(16) unsigned short Bh[128 * LDSTR];
    const int t = threadIdx.x;
    const int wave = t >> 6, lane = t & 63;
    const int m0 = blockIdx.y * 128, n0 = blockIdx.x * 128;
    const int wm = (wave >> 1) * 64, wn = (wave & 1) * 64;
    const int fr = lane & 15, kq = lane >> 4;

    f32x4 acc[4][4];
    #pragma unroll
    for (int i = 0; i < 4; ++i)
        #pragma unroll
        for (int j = 0; j < 4; ++j)
            acc[i][j] = (f32x4){0.f, 0.f, 0.f, 0.f};

    const int srow = t >> 3;
    const int scol = (t & 7) * 4;

    for (int k0 = 0; k0 < K; k0 += 32) {
        #pragma unroll
        for (int p = 0; p < 4; ++p) {
            const int row = p * 32 + srow;
            const float4 av = *reinterpret_cast<const float4*>(
                A + (size_t)(m0 + row) * lda + k0 + scol);
            ushort4 a4;
            a4.x = f2b(av.x); a4.y = f2b(av.y); a4.z = f2b(av.z); a4.w = f2b(av.w);
            *reinterpret_cast<ushort4*>(&Ah[row * LDSTR + scol]) = a4;
            const float4 bv = *reinterpret_cast<const float4*>(
                B + (size_t)(n0 + row) * ldb + k0 + scol);
            ushort4 b4;
            b4.x = f2b(bv.x); b4.y = f2b(bv.y); b4.z = f2b(bv.z); b4.w = f2b(bv.w);
            *reinterpret_cast<ushort4*>(&Bh[row * LDSTR + scol]) = b4;
        }
        __syncthreads();

        bf16x8 af[4], bfr[4];
        #pragma unroll
        for (int mi = 0; mi < 4; ++mi)
            af[mi] = *reinterpret_cast<const bf16x8*>(&Ah[(wm + mi * 16 + fr) * LDSTR + kq * 8]);
        #pragma unroll
        for (int ni = 0; ni < 4; ++ni)
            bfr[ni] = *reinterpret_cast<const bf16x8*>(&Bh[(wn + ni * 16 + fr) * LDSTR + kq * 8]);
        #pragma unroll
        for (int mi = 0; mi < 4; ++mi)
            #pragma unroll
            for (int ni = 0; ni < 4; ++ni)
                acc[mi][ni] = __builtin_amdgcn_mfma_f32_16x16x32_bf16(
                    af[mi], bfr[ni], acc[mi][ni], 0, 0, 0);
        __syncthreads();
    }

    const int crow0 = m0 + wm + kq * 4;
    const int ccol0 = n0 + wn + fr;
    #pragma unroll
    for (int mi = 0; mi < 4; ++mi)
        #pragma unroll
        for (int ni = 0; ni < 4; ++ni) {
            const int col = ccol0 + ni * 16;
            #pragma unroll
            for (int i = 0; i < 4; ++i)
                C[(size_t)(crow0 + mi * 16 + i) * ldc + col] = acc[mi][ni][i];
        }
}

// ---------------------------------------------------------------------------
// Batched stage-2 GEMM: z=0: dd ; z=1: aa ; z=2: vv.
// ---------------------------------------------------------------------------
__global__ __launch_bounds__(256) void gemm_stage2(
    const float* __restrict__ kvh,
    const float* __restrict__ w2T, const float* __restrict__ a2T,
    const float* __restrict__ v2T,
    float* __restrict__ wdec, float* __restrict__ kf, float* __restrict__ vf)
{
    const int z = blockIdx.z;
    const float* A = kvh + (z == 0 ? 512 : z == 1 ? 576 : 640);
    const float* B = z == 0 ? w2T : z == 1 ? a2T : v2T;
    float* C       = z == 0 ? wdec : z == 1 ? kf : vf;
    const int K    = z == 2 ? 32 : 64;
    const int ldb  = K;

    __shared__ __align__(16) unsigned short Ah[128 * LDSTR];
    __shared__ __align__(16) unsigned short Bh[128 * LDSTR];
    const int t = threadIdx.x;
    const int wave = t >> 6, lane = t & 63;
    const int m0 = blockIdx.y * 128, n0 = blockIdx.x * 128;
    const int wm = (wave >> 1) * 64, wn = (wave & 1) * 64;
    const int fr = lane & 15, kq = lane >> 4;

    f32x4 acc[4][4];
    #pragma unroll
    for (int i = 0; i < 4; ++i)
        #pragma unroll
        for (int j = 0; j < 4; ++j)
            acc[i][j] = (f32x4){0.f, 0.f, 0.f, 0.f};

    const int srow = t >> 3;
    const int scol = (t & 7) * 4;

    for (int k0 = 0; k0 < K; k0 += 32) {
        #pragma unroll
        for (int p = 0; p < 4; ++p) {
            const int row = p * 32 + srow;
            const float4 av = *reinterpret_cast<const float4*>(
                A + (size_t)(m0 + row) * 672 + k0 + scol);
            ushort4 a4;
            a4.x = f2b(av.x); a4.y = f2b(av.y); a4.z = f2b(av.z); a4.w = f2b(av.w);
            *reinterpret_cast<ushort4*>(&Ah[row * LDSTR + scol]) = a4;
            const float4 bv = *reinterpret_cast<const float4*>(
                B + (size_t)(n0 + row) * ldb + k0 + scol);
            ushort4 b4;
            b4.x = f2b(bv.x); b4.y = f2b(bv.y); b4.z = f2b(bv.z); b4.w = f2b(bv.w);
            *reinterpret_cast<ushort4*>(&Bh[row * LDSTR + scol]) = b4;
        }
        __syncthreads();

        bf16x8 af[4], bfr[4];
        #pragma unroll
        for (int mi = 0; mi < 4; ++mi)
            af[mi] = *reinterpret_cast<const bf16x8*>(&Ah[(wm + mi * 16 + fr) * LDSTR + kq * 8]);
        #pragma unroll
        for (int ni = 0; ni < 4; ++ni)
            bfr[ni] = *reinterpret_cast<const bf16x8*>(&Bh[(wn + ni * 16 + fr) * LDSTR + kq * 8]);
        #pragma unroll
        for (int mi = 0; mi < 4; ++mi)
            #pragma unroll
            for (int ni = 0; ni < 4; ++ni)
                acc[mi][ni] = __builtin_amdgcn_mfma_f32_16x16x32_bf16(
                    af[mi], bfr[ni], acc[mi][ni], 0, 0, 0);
        __syncthreads();
    }

    const int crow0 = m0 + wm + kq * 4;
    const int ccol0 = n0 + wn + fr;
    #pragma unroll
    for (int mi = 0; mi < 4; ++mi)
        #pragma unroll
        for (int ni = 0; ni < 4; ++ni) {
            const int col = ccol0 + ni * 16;
            #pragma unroll
            for (int i = 0; i < 4; ++i)
                C[(size_t)(crow0 + mi * 16 + i) * 1024 + col] = acc[mi][ni][i];
        }
}

// ---------------------------------------------------------------------------
// Weight packing.
// ---------------------------------------------------------------------------
__global__ __launch_bounds__(256) void pack_all(
    const float* __restrict__ Wk, const float* __restrict__ Wv,
    const float* __restrict__ w1, const float* __restrict__ a1,
    const float* __restrict__ v1, const float* __restrict__ w2,
    const float* __restrict__ a2, const float* __restrict__ v2,
    float* __restrict__ Wkvh,
    float* __restrict__ w2T, float* __restrict__ a2T, float* __restrict__ v2T)
{
    const int blk = blockIdx.x, t = threadIdx.x;
    if (blk < 512) {
        const float* s = blk < 256 ? Wk + (size_t)blk * 1024
                                   : Wv + (size_t)(blk - 256) * 1024;
        const float4 v = *reinterpret_cast<const float4*>(s + t * 4);
        *reinterpret_cast<float4*>(Wkvh + (size_t)blk * 1024 + t * 4) = v;
    } else if (blk < 672) {
        const int f = blk - 512;     // 0..159
        for (int c = t; c < 1024; c += 256) {
            float val;
            if (f < 64)       val = w1[c * 64 + f];
            else if (f < 128) val = a1[c * 64 + (f - 64)];
            else              val = v1[c * 32 + (f - 128)];
            Wkvh[(size_t)(512 + f) * 1024 + c] = val;
        }
    } else {
        const int c = blk - 672;     // 0..1023
        if (t < 64)       w2T[c * 64 + t]         = w2[t * 1024 + c];
        else if (t < 128) a2T[c * 64 + (t - 64)]  = a2[(t - 64) * 1024 + c];
        else if (t < 160) v2T[c * 32 + (t - 128)] = v2[(t - 128) * 1024 + c];
    }
}

// ---------------------------------------------------------------------------
// Slim fuse_pre (aliased in-place dd/aa/vv — read idx then write idx).
// Also writes the v_first passthrough to out2.
// ---------------------------------------------------------------------------
__global__ __launch_bounds__(256) void fuse_pre(
    const float* __restrict__ kvh,
    const float* __restrict__ v_first, const float* __restrict__ mask,
    const float* __restrict__ w0, const float* __restrict__ a0,
    const float* __restrict__ v0,
    const float* __restrict__ k_k, const float* __restrict__ k_a,
    float* __restrict__ wdec, float* __restrict__ kf, float* __restrict__ vf,
    float* __restrict__ aab, float* __restrict__ bbb,
    float* __restrict__ out2)
{
    const int n = blockIdx.x, t = threadIdx.x;
    const float m = mask[n];
    const bool live = m > 0.f;

    #pragma unroll
    for (int q = 0; q < 4; ++q) {
        const int c = q * 256 + t;
        const size_t idx = (size_t)n * 1024 + c;
        const float dd   = w0[c] + wdec[idx];   // ddl
        const float aacc = a0[c] + kf[idx];     // aal
        const float vacc = v0[c] + vf[idx];     // vvl

        const float u  = -dd;
        const float sp = fmaxf(u, 0.f) + log1pf(expf(-fabsf(u)));
        const float dec = expf(-expf(-sp - 0.6f));
        const float av = 1.f / (1.f + expf(-aacc));
        const float sv = 1.f / (1.f + expf(-vacc));

        const int  ck  = q * 64 + (c & 63);
        const float kr = kvh[(size_t)n * 672 + ck];
        const float vr = kvh[(size_t)n * 672 + 256 + ck];
        const float vfi = v_first[idx];
        const float vv  = vr + (vfi - vr) * sv;

        const float tkk = kr * k_k[c];
        float ss = tkk * tkk;
        #pragma unroll
        for (int off = 32; off > 0; off >>= 1) ss += __shfl_xor(ss, off, 64);
        const float kkv = tkk / fmaxf(sqrtf(ss), 1e-12f);

        wdec[idx] = live ? dec : 1.f;
        kf[idx]   = kr * (1.f + (av - 1.f) * k_a[c]) * m;
        vf[idx]   = vv * m;
        aab[idx]  = -kkv * m;
        bbb[idx]  = kkv * av * m;
        out2[idx] = vfi;                       // v_first passthrough
    }
}

// ---------------------------------------------------------------------------
// WKV7 (session best, 235us): 256 blocks x 4 waves; wave = (bh, j-quarter,
// 4 rows). LDS 8-step double-buffered groups + 1-ahead ds_read pipeline
// (named C/N regs, compile-time indices). Per group ONE vmcnt(8) + ONE raw
// s_barrier. XCD swizzle: 4 blocks of a bh share blk%8.
// ---------------------------------------------------------------------------
__device__ __forceinline__ float qred16(float x) {
    x += __int_as_float(__builtin_amdgcn_update_dpp(
        0, __float_as_int(x), 0xB1, 0xF, 0xF, true));   // quad_perm xor1
    x += __int_as_float(__builtin_amdgcn_update_dpp(
        0, __float_as_int(x), 0x4E, 0xF, 0xF, true));   // quad_perm xor2
    x += __int_as_float(__builtin_amdgcn_update_dpp(
        0, __float_as_int(x), 0x141, 0xF, 0xF, true));  // row_half_mirror
    x += __int_as_float(__builtin_amdgcn_update_dpp(
        0, __float_as_int(x), 0x140, 0xF, 0xF, true));  // row_mirror
    return x;
}

__global__ __launch_bounds__(256, 1) void wkv7(
    const float* __restrict__ r, const float* __restrict__ wdec,
    const float* __restrict__ kf, const float* __restrict__ vf,
    const float* __restrict__ aab, const float* __restrict__ bbb,
    float* __restrict__ y)
{
    __shared__ __align__(16) float4 sl[2][672];
    const int blk = blockIdx.x;               // 0..255
    const int m  = blk & 7;
    const int s_ = blk >> 3;                  // 0..31
    const int bh = (s_ >> 2) * 8 + m;         // 4 blocks of bh share m -> same XCD
    const int j  = s_ & 3;
    const int b = bh >> 4, h = bh & 15;
    const int tid  = threadIdx.x;
    const int wave = tid >> 6;
    const int lane = tid & 63;
    const int li   = lane & 15;
    const int il   = wave * 4 + (lane >> 4);  // local row 0..15
    const int i    = j * 16 + il;             // value row 0..63
    const size_t cb = (size_t)b * (1024 * 1024) + (size_t)h * 64;

#define GLL16(g, l) __builtin_amdgcn_global_load_lds( \
        (const __attribute__((address_space(1))) unsigned int*)(g), \
        (__attribute__((address_space(3))) unsigned int*)(l), 16, 0, 0)

    // cooperative stage of steps [t0, t0+8) into buffer bf
    auto stage = [&](int t0, int bf) {
        #pragma unroll
        for (int k = 0; k < 3; ++k) {
            const int q = tid + k * 256;
            if (q < 672) {
                const float* gp;
                if (q < 640) {
                    const int s  = q / 80;
                    const int rm = q - s * 80;
                    const int arr = rm >> 4, c16 = rm & 15;
                    const float* base = arr == 0 ? wdec : arr == 1 ? kf
                                      : arr == 2 ? aab : arr == 3 ? bbb : r;
                    gp = base + cb + (size_t)(t0 + s) * 1024 + c16 * 4;
                } else {
                    const int qq = q - 640;
                    const int s = qq >> 2, c4 = qq & 3;
                    gp = vf + cb + (size_t)(t0 + s) * 1024 + j * 16 + c4 * 4;
                }
                // wave-uniform LDS base: slot (wave*64 + k*256); HW adds lane*16
                GLL16(gp, &sl[bf][wave * 64 + k * 256]);
            }
        }
    };

    float4 S = (float4){0.f, 0.f, 0.f, 0.f};

    stage(0, 0);
    asm volatile("s_waitcnt vmcnt(0)" ::: "memory");
    __builtin_amdgcn_sched_barrier(0);
    __builtin_amdgcn_s_barrier();

    for (int g = 0; g < 128; ++g) {
        const int bf = g & 1;
        const int t0 = g * 8;
        if (g + 1 < 128) stage(t0 + 8, bf ^ 1);
        __builtin_amdgcn_sched_barrier(0);   // pin GLLs before compute

        // preload step 0 of the group
        float4 dC = sl[bf][0  + li];
        float4 kC = sl[bf][16 + li];
        float4 aC = sl[bf][32 + li];
        float4 bC = sl[bf][48 + li];
        float4 rC = sl[bf][64 + li];
        float  vC = reinterpret_cast<const float*>(&sl[bf][640])[il];

        #pragma unroll
        for (int s = 0; s < 8; ++s) {
            // issue step s+1's reads before computing step s (1-ahead pipeline)
            float4 dN, kN, aN, bN, rN; float vN;
            if (s < 7) {
                dN = sl[bf][(s + 1) * 80 + 0  + li];
                kN = sl[bf][(s + 1) * 80 + 16 + li];
                aN = sl[bf][(s + 1) * 80 + 32 + li];
                bN = sl[bf][(s + 1) * 80 + 48 + li];
                rN = sl[bf][(s + 1) * 80 + 64 + li];
                vN = reinterpret_cast<const float*>(&sl[bf][640 + (s + 1) * 4])[il];
            }

            float sa = S.x * aC.x + S.y * aC.y + S.z * aC.z + S.w * aC.w;
            sa = qred16(sa);
            S.x = S.x * dC.x + sa * bC.x + vC * kC.x;
            S.y = S.y * dC.y + sa * bC.y + vC * kC.y;
            S.z = S.z * dC.z + sa * bC.z + vC * kC.z;
            S.w = S.w * dC.w + sa * bC.w + vC * kC.w;
            float yv = S.x * rC.x + S.y * rC.y + S.z * rC.z + S.w * rC.w;
            yv = qred16(yv);
            if (li == 0) y[cb + (size_t)(t0 + s) * 1024 + i] = yv;

            if (s < 7) { dC = dN; kC = kN; aC = aN; bC = bN; rC = rN; vC = vN; }
        }

        // retire this group's 3 staged GLLs; the <=8 newest (y-stores) may remain
        asm volatile("s_waitcnt vmcnt(8)" ::: "memory");
        __builtin_amdgcn_sched_barrier(0);
        __builtin_amdgcn_s_barrier();
    }
#undef GLL16
}

// ---------------------------------------------------------------------------
// Post: groupnorm per (row, head) + rk*v residual
// ---------------------------------------------------------------------------
__global__ __launch_bounds__(256) void fuse_post(
    const float* __restrict__ y, const float* __restrict__ r,
    const float* __restrict__ kf, const float* __restrict__ vf,
    const float* __restrict__ r_k, const float* __restrict__ ln_g, const float* __restrict__ ln_b,
    float* __restrict__ yn)
{
    const int n = blockIdx.x, t = threadIdx.x;
    #pragma unroll
    for (int q = 0; q < 4; ++q) {
        const int c = q * 256 + t;
        const size_t idx = (size_t)n * 1024 + c;
        const float yv = y[idx];
        float s1 = yv, s2 = yv * yv;
        float rk = r[idx] * kf[idx] * r_k[c];
        #pragma unroll
        for (int off = 32; off > 0; off >>= 1) {
            s1 += __shfl_xor(s1, off, 64);
            s2 += __shfl_xor(s2, off, 64);
            rk += __shfl_xor(rk, off, 64);
        }
        const float mu  = s1 * (1.f / 64.f);
        const float var = s2 * (1.f / 64.f) - mu * mu;
        yn[idx] = (yv - mu) * rsqrtf(var + EPSV) * ln_g[c] + ln_b[c]
                  + rk * vf[idx];
    }
}

// ---------------------------------------------------------------------------
extern "C" void kernel_launch(void* const* d_in, const int* in_sizes, int n_in,
                              void* d_out, int out_size, void* d_ws, size_t ws_size,
                              hipStream_t stream)
{
    const float* x       = (const float*)d_in[0];
    const float* v_first = (const float*)d_in[1];
    const float* mask    = (const float*)d_in[2];
    const float* Wr      = (const float*)d_in[3];
    const float* Wk      = (const float*)d_in[4];
    const float* Wv      = (const float*)d_in[5];
    const float* Wo      = (const float*)d_in[6];
    const float* w0      = (const float*)d_in[7];
    const float* w1      = (const float*)d_in[8];
    const float* w2      = (const float*)d_in[9];
    const float* a0      = (const float*)d_in[10];
    const float* a1      = (const float*)d_in[11];
    const float* a2      = (const float*)d_in[12];
    const float* v0      = (const float*)d_in[13];
    const float* v1      = (const float*)d_in[14];
    const float* v2      = (const float*)d_in[15];
    const float* k_k     = (const float*)d_in[16];
    const float* k_a     = (const float*)d_in[17];
    const float* r_k     = (const float*)d_in[18];
    const float* ln_g    = (const float*)d_in[19];
    const float* ln_b    = (const float*)d_in[20];
    float* out = (float*)d_out;

    float* ws = (float*)d_ws;
    const size_t M4 = (size_t)NROWS * CCH;   // 4M elements
    float* rbuf = ws;
    float* wdec = ws + 1 * M4;   // pre-fuse_pre: ddl
    float* kf   = ws + 2 * M4;   // pre-fuse_pre: aal
    float* vf   = ws + 3 * M4;   // pre-fuse_pre: vvl
    float* aab  = ws + 4 * M4;   // post-wkv7: yn
    float* bbb  = ws + 5 * M4;
    float* ybuf = ws + 6 * M4;
    // region-6 temps (dead before wkv7 writes ybuf):
    float* kvh  = ybuf;                          // [4096][672]
    float* w2T  = kvh  + (size_t)NROWS * 672;    // [1024][64]
    float* a2T  = w2T  + (size_t)1024 * 64;      // [1024][64]
    float* v2T  = a2T  + (size_t)1024 * 64;      // [1024][32]
    float* Wkvh = v2T  + (size_t)1024 * 32;      // [672][1024]
    float* yn = aab;

    dim3 blk(256);
    pack_all<<<1696, blk, 0, stream>>>(Wk, Wv, w1, a1, v1, w2, a2, v2,
                                       Wkvh, w2T, a2T, v2T);
    gemm_mfma<<<dim3(8, 32), blk, 0, stream>>>(
        x, 1024, Wr, 1024, rbuf, 1024, NROWS, 1024, 1024);
    gemm_split<true><<<dim3(6, 32), blk, 0, stream>>>(
        x, 1024, Wkvh, 1024, kvh, 672, NROWS, 672, 1024, 512, 576);
    gemm_stage2<<<dim3(8, 32, 3), blk, 0, stream>>>(
        kvh, w2T, a2T, v2T, wdec, kf, vf);
    fuse_pre<<<NROWS, blk, 0, stream>>>(kvh, v_first, mask, w0, a0, v0,
                                        k_k, k_a, wdec, kf, vf, aab, bbb,
                                        out + M4);
    wkv7<<<256, blk, 0, stream>>>(rbuf, wdec, kf, vf, aab, bbb, ybuf);
    fuse_post<<<NROWS, blk, 0, stream>>>(ybuf, rbuf, kf, vf, r_k, ln_g, ln_b, yn);
    gemm_mfma<<<dim3(8, 32), blk, 0, stream>>>(
        yn, 1024, Wo, 1024, out, 1024, NROWS, 1024, 1024);
}